// Round 14
// baseline (829.876 us; speedup 1.0000x reference)
//
#include <hip/hip_runtime.h>
#include <stdint.h>

#define DEVI __device__ __forceinline__

typedef __attribute__((ext_vector_type(8))) short short8;
typedef __attribute__((ext_vector_type(4))) float f32x4;
typedef unsigned short u16;
typedef unsigned int u32;

typedef const __attribute__((address_space(1))) void* gas_ptr;
typedef __attribute__((address_space(3))) void* las_ptr;

constexpr int BBATCH = 2;
constexpr int TT  = 1024;
constexpr int BT  = BBATCH * TT;   // 2048 tokens
constexpr int DM  = 1024;
constexpr int NH  = 16;
constexpr int HD  = 64;
constexpr int DFF = 4096;
constexpr int NV  = 32000;
constexpr int NL  = 4;

DEVI u16 f2b(float f) {
  u32 u = __builtin_bit_cast(u32, f);
  u = (u + 0x7fffu + ((u >> 16) & 1u)) >> 16;
  return (u16)u;
}
DEVI float b2f(u16 h) { return __builtin_bit_cast(float, (u32)h << 16); }

DEVI void gld16(const void* g, void* l) {
  __builtin_amdgcn_global_load_lds((gas_ptr)g, (las_ptr)l, 16, 0, 0);
}

DEVI float wave_sum(float v) {
#pragma unroll
  for (int off = 32; off; off >>= 1) v += __shfl_xor(v, off);
  return v;
}
DEVI float block_sum(float v, float* sb) {
  v = wave_sum(v);
  int lane = threadIdx.x & 63, wid = threadIdx.x >> 6;
  __syncthreads();
  if (lane == 0) sb[wid] = v;
  __syncthreads();
  return sb[0] + sb[1] + sb[2] + sb[3];
}

DEVI float gelu_f(float x) {
  float u = 0.7978845608028654f * (x + 0.044715f * x * x * x);
  float e = __expf(2.0f * u);            // gelu = x * sigmoid(2u)
  return x * (1.0f - 1.0f / (e + 1.0f));
}

// ---------------- fused: weight transpose+convert (f32 [K][N] -> bf16 [N][K])
// + embedding gather + LayerNorm (blocks >= 22144) ----------------
__global__ __launch_bounds__(256) void wt_embed_all(
    const float* __restrict__ Wqkv, const float* __restrict__ Wo,
    const float* __restrict__ W1, const float* __restrict__ W2,
    const float* __restrict__ Wlm,
    u16* __restrict__ WqkvT, u16* __restrict__ WoT, u16* __restrict__ W1T,
    u16* __restrict__ W2T, u16* __restrict__ WlmT,
    const int* __restrict__ idx, const float* __restrict__ tok,
    const float* __restrict__ ln_g, const float* __restrict__ ln_b,
    float* __restrict__ x) {
  __shared__ float t[64][33];
  int bid = blockIdx.x;
  if (bid >= 22144) {
    // embedding gather + LayerNorm for token row (bid - 22144)
    int row = bid - 22144, tid = threadIdx.x;
    float* sb = &t[0][0];
    float4 v = ((const float4*)(tok + (size_t)idx[row] * DM))[tid];
    float s = block_sum(v.x + v.y + v.z + v.w, sb);
    float m = s * (1.0f / DM);
    float dx = v.x - m, dy = v.y - m, dz = v.z - m, dw = v.w - m;
    float q = block_sum(dx * dx + dy * dy + dz * dz + dw * dw, sb);
    float rs = rsqrtf(q * (1.0f / DM) + 1e-5f);
    float4 gg = ((const float4*)ln_g)[tid];
    float4 bb = ((const float4*)ln_b)[tid];
    float4 o = make_float4(dx * rs * gg.x + bb.x, dy * rs * gg.y + bb.y,
                           dz * rs * gg.z + bb.z, dw * rs * gg.w + bb.w);
    ((float4*)(x + (size_t)row * DM))[tid] = o;
    return;
  }
  const float* in; u16* out; int K, N, tt;
  if (bid < 1536)      { in = Wqkv; out = WqkvT; K = 1024; N = 3072;  tt = bid; }
  else if (bid < 2048) { in = Wo;   out = WoT;   K = 1024; N = 1024;  tt = bid - 1536; }
  else if (bid < 4096) { in = W1;   out = W1T;   K = 1024; N = 4096;  tt = bid - 2048; }
  else if (bid < 6144) { in = W2;   out = W2T;   K = 4096; N = 1024;  tt = bid - 4096; }
  else                 { in = Wlm;  out = WlmT;  K = 1024; N = 32000; tt = bid - 6144; }
  int nx = N >> 5;
  int n0 = (tt % nx) * 32, k0 = (tt / nx) * 64;
  int tx = threadIdx.x & 31, ty = threadIdx.x >> 5;   // ty 0..7
#pragma unroll
  for (int i = 0; i < 8; ++i)
    t[ty + 8 * i][tx] = in[(size_t)(k0 + ty + 8 * i) * N + n0 + tx];
  __syncthreads();
#pragma unroll
  for (int i = 0; i < 4; ++i) {
    int r = ty + 8 * i;                               // n-local 0..31
    u32 pk = (u32)f2b(t[2 * tx][r]) | ((u32)f2b(t[2 * tx + 1][r]) << 16);
    *(u32*)(out + (size_t)(n0 + r) * K + k0 + 2 * tx) = pk;
  }
}

// ---------------- final LayerNorm -> bf16 ----------------
__global__ __launch_bounds__(256) void final_ln_k(const float* __restrict__ x,
                                                  const float* __restrict__ g,
                                                  const float* __restrict__ b,
                                                  u16* __restrict__ xf) {
  __shared__ float sb[4];
  int row = blockIdx.x, tid = threadIdx.x;
  float4 v = ((const float4*)(x + (size_t)row * DM))[tid];
  float s = block_sum(v.x + v.y + v.z + v.w, sb);
  float m = s * (1.0f / DM);
  float dx = v.x - m, dy = v.y - m, dz = v.z - m, dw = v.w - m;
  float q = block_sum(dx * dx + dy * dy + dz * dz + dw * dw, sb);
  float rs = rsqrtf(q * (1.0f / DM) + 1e-5f);
  float4 gg = ((const float4*)g)[tid];
  float4 bb = ((const float4*)b)[tid];
  u32 lo = (u32)f2b(dx * rs * gg.x + bb.x) | ((u32)f2b(dy * rs * gg.y + bb.y) << 16);
  u32 hi = (u32)f2b(dz * rs * gg.z + bb.z) | ((u32)f2b(dw * rs * gg.w + bb.w) << 16);
  ((uint2*)(xf + (size_t)row * DM))[tid] = make_uint2(lo, hi);
}

// ---------------- RMSNorm f32 -> bf16 ----------------
__global__ __launch_bounds__(256) void rmsnorm_k(const float* __restrict__ x,
                                                 const float* __restrict__ w,
                                                 u16* __restrict__ h) {
  __shared__ float sb[4];
  int row = blockIdx.x, tid = threadIdx.x;
  float4 v = ((const float4*)(x + (size_t)row * DM))[tid];
  float q = block_sum(v.x * v.x + v.y * v.y + v.z * v.z + v.w * v.w, sb);
  float rs = rsqrtf(q * (1.0f / DM) + 1.1920928955078125e-7f);
  float4 ww = ((const float4*)w)[tid];
  u32 lo = (u32)f2b(v.x * rs * ww.x) | ((u32)f2b(v.y * rs * ww.y) << 16);
  u32 hi = (u32)f2b(v.z * rs * ww.z) | ((u32)f2b(v.w * rs * ww.w) << 16);
  ((uint2*)(h + (size_t)row * DM))[tid] = make_uint2(lo, hi);
}

// ---------------- fused flash attention, QBLK=64, double-buffered KV (r13-validated) ----------------
__global__ __launch_bounds__(256) void attn_k(const u16* __restrict__ qkv,
                                              const u16* __restrict__ vT,
                                              u16* __restrict__ y) {
  __shared__ __align__(16) char sP[16384];      // Q [64][128B] swz8, then P [64][256B] swz16
  __shared__ __align__(16) char sK[2][16384];   // K tile [128][128B] swz8
  __shared__ __align__(16) char sV[2][16384];   // Vt tile [64][256B] swz16
  const int tid = threadIdx.x, lane = tid & 63, wid = tid >> 6;
  const int bid = blockIdx.x;
  const int sl = (bid + (bid >> 8)) & 15;
  const int qt = (sl & 1) ? (sl >> 1) : (15 - (sl >> 1));   // balanced pairing
  const int bh = (bid >> 4) & 31, b = bh >> 4, h = bh & 15;
  const int nt = (qt >> 1) + 1;                             // kv tiles (128 wide)
  const float slope = exp2f(-0.5f * (float)(h + 1));

  const char* Qb = (const char*)(qkv + (size_t)b * TT * 3 * DM + h * HD);
  const char* Kb = (const char*)(qkv + (size_t)b * TT * 3 * DM + DM + h * HD);
  const char* Vb = (const char*)(vT + (size_t)bh * HD * TT);

#pragma unroll
  for (int ci = 0; ci < 2; ++ci) {
    int c = wid * 2 + ci;
    int r = c * 8 + (lane >> 3);
    int q = (lane & 7) ^ (r & 7);
    gld16(Qb + (size_t)(qt * 64 + r) * 6144 + q * 16, sP + c * 1024 + lane * 16);
  }

  auto stageKV = [&](int buf, int kt) {
    int kv0 = kt * 128;
#pragma unroll
    for (int ci = 0; ci < 4; ++ci) {            // K: [128][128B]
      int c = wid * 4 + ci;
      int r = c * 8 + (lane >> 3);
      int q = (lane & 7) ^ (r & 7);
      gld16(Kb + (size_t)(kv0 + r) * 6144 + q * 16, sK[buf] + c * 1024 + lane * 16);
    }
#pragma unroll
    for (int ci = 0; ci < 4; ++ci) {            // Vt: [64][256B]
      int c = wid * 4 + ci;
      int d = c * 4 + (lane >> 4);
      int q = (lane & 15) ^ (d & 15);
      gld16(Vb + (size_t)d * 2048 + (size_t)kv0 * 2 + q * 16, sV[buf] + c * 1024 + lane * 16);
    }
  };
  stageKV(0, 0);
  asm volatile("s_waitcnt vmcnt(8)" ::: "memory");   // Q's 2 loads (oldest) done

  short8 qf[2];
#pragma unroll
  for (int ks = 0; ks < 2; ++ks) {
    int r = wid * 16 + (lane & 15);
    int q = ((ks << 2) + (lane >> 4)) ^ (r & 7);
    qf[ks] = *(const short8*)(sP + r * 128 + q * 16);
  }

  f32x4 Y[4] = {};
  float m_r[4], l_r[4];
#pragma unroll
  for (int r = 0; r < 4; ++r) { m_r[r] = -3e38f; l_r[r] = 0.0f; }

  for (int kt = 0; kt < nt; ++kt) {
    const int cur = kt & 1;
    if (kt + 1 < nt) {
      stageKV(cur ^ 1, kt + 1);                      // prefetch next tile
      asm volatile("s_waitcnt vmcnt(8)" ::: "memory");  // wait current tile only
    } else {
      asm volatile("s_waitcnt vmcnt(0)" ::: "memory");
    }
    __syncthreads();   // publish tile kt (and: Q regs loaded before any P write)

    // QK^T
    f32x4 s[8] = {};
    __builtin_amdgcn_s_setprio(1);
#pragma unroll
    for (int ks = 0; ks < 2; ++ks) {
      short8 kf[8];
#pragma unroll
      for (int j = 0; j < 8; ++j) {
        int r = j * 16 + (lane & 15);
        int q = ((ks << 2) + (lane >> 4)) ^ (r & 7);
        kf[j] = *(const short8*)(sK[cur] + r * 128 + q * 16);
      }
#pragma unroll
      for (int j = 0; j < 8; ++j)
        s[j] = __builtin_amdgcn_mfma_f32_16x16x32_bf16(qf[ks], kf[j], s[j], 0, 0, 0);
    }
    __builtin_amdgcn_s_setprio(0);

    // scale + row-invariant ALiBi (+slope*kcol) + causal mask + online softmax
    const int kv0 = kt * 128;
    const int qbase = qt * 64 + wid * 16 + ((lane >> 4) << 2);
    float colb[8];
#pragma unroll
    for (int j = 0; j < 8; ++j)
      colb[j] = slope * (float)(kv0 + j * 16 + (lane & 15));
    float rowmax[4] = {-3e38f, -3e38f, -3e38f, -3e38f};
    if (kv0 + 127 <= qt * 64) {
#pragma unroll
      for (int j = 0; j < 8; ++j)
#pragma unroll
        for (int r = 0; r < 4; ++r) {
          float v = fmaf(s[j][r], 0.125f, colb[j]);
          s[j][r] = v;
          rowmax[r] = fmaxf(rowmax[r], v);
        }
    } else {
#pragma unroll
      for (int j = 0; j < 8; ++j) {
        int kcol = kv0 + j * 16 + (lane & 15);
#pragma unroll
        for (int r = 0; r < 4; ++r) {
          float v = (kcol <= qbase + r) ? fmaf(s[j][r], 0.125f, colb[j]) : -3e38f;
          s[j][r] = v;
          rowmax[r] = fmaxf(rowmax[r], v);
        }
      }
    }
#pragma unroll
    for (int r = 0; r < 4; ++r) {
      rowmax[r] = fmaxf(rowmax[r], __shfl_xor(rowmax[r], 1));
      rowmax[r] = fmaxf(rowmax[r], __shfl_xor(rowmax[r], 2));
      rowmax[r] = fmaxf(rowmax[r], __shfl_xor(rowmax[r], 4));
      rowmax[r] = fmaxf(rowmax[r], __shfl_xor(rowmax[r], 8));
      float mn = fmaxf(m_r[r], rowmax[r]);
      float al = __expf(m_r[r] - mn);
      m_r[r] = mn;
      l_r[r] *= al;
#pragma unroll
      for (int j = 0; j < 4; ++j) Y[j][r] *= al;
    }
    float rs[4] = {0.0f, 0.0f, 0.0f, 0.0f};
#pragma unroll
    for (int j = 0; j < 8; ++j)
#pragma unroll
      for (int r = 0; r < 4; ++r) {
        float p = __expf(s[j][r] - m_r[r]);
        s[j][r] = p;
        rs[r] += p;
      }
#pragma unroll
    for (int r = 0; r < 4; ++r) {
      rs[r] += __shfl_xor(rs[r], 1);
      rs[r] += __shfl_xor(rs[r], 2);
      rs[r] += __shfl_xor(rs[r], 4);
      rs[r] += __shfl_xor(rs[r], 8);
      l_r[r] += rs[r];
    }
    // write P (bf16) to own sP rows, swz16 over 256B rows
#pragma unroll
    for (int j = 0; j < 8; ++j)
#pragma unroll
      for (int r = 0; r < 4; ++r) {
        int rl = wid * 16 + ((lane >> 4) << 2) + r;
        int c = j * 16 + (lane & 15);
        int g = c >> 3;
        *(u16*)(sP + rl * 256 + ((g ^ (rl & 15)) << 4) + (c & 7) * 2) = f2b(s[j][r]);
      }

    // PV: Y += P(own rows) * Vt
    __builtin_amdgcn_s_setprio(1);
#pragma unroll
    for (int ks = 0; ks < 4; ++ks) {
      short8 pf, vf[4];
      {
        int r = wid * 16 + (lane & 15);
        int q = ((ks << 2) + (lane >> 4)) ^ (r & 15);
        pf = *(const short8*)(sP + r * 256 + (q << 4));
      }
#pragma unroll
      for (int j = 0; j < 4; ++j) {
        int d = j * 16 + (lane & 15);
        int q = ((ks << 2) + (lane >> 4)) ^ (d & 15);
        vf[j] = *(const short8*)(sV[cur] + d * 256 + (q << 4));
      }
#pragma unroll
      for (int j = 0; j < 4; ++j)
        Y[j] = __builtin_amdgcn_mfma_f32_16x16x32_bf16(pf, vf[j], Y[j], 0, 0, 0);
    }
    __builtin_amdgcn_s_setprio(0);
    __syncthreads();   // all waves done reading bufs[cur] + sP before next overwrite
  }

  // epilogue: y[b, qrow, h*64 + d] = Y / l
#pragma unroll
  for (int r = 0; r < 4; ++r) {
    float inv = 1.0f / l_r[r];
    int qrow = qt * 64 + wid * 16 + ((lane >> 4) << 2) + r;
    u16* yp = y + (size_t)(b * TT + qrow) * DM + h * HD;
#pragma unroll
    for (int j = 0; j < 4; ++j)
      yp[j * 16 + (lane & 15)] = f2b(Y[j][r] * inv);
  }
}

// ---------------- GEMM epilogue variants ----------------
enum { EPI_BF16 = 0, EPI_GELU = 1, EPI_ADDF32 = 2, EPI_F32 = 3, EPI_ATOMIC = 4, EPI_QKV = 5 };

// ---------------- 2/3-deep 128-tile GEMM + split-K + fused V-transpose ----------------
// STAGES=3 (QKV/Wo shapes, 24KiB/buf -> 72KiB, keeps 2 blocks/CU): 2-tile lookahead,
// counted vmcnt(6) (= one stage's 6 gld16 outstanding), one barrier/iter at top;
// stage((t+2)%3) issued after the barrier so all compute(t-1) readers are done.
template <int BM, int BN, int WM, int WN, int EPI, int KS = 1, int STAGES = 2>
__global__ __launch_bounds__(256, 2) void gemm_bt(
    const u16* __restrict__ A, int lda, const u16* __restrict__ Bt, int ldb,
    const float* __restrict__ bias, void* __restrict__ C, int ldc,
    float* __restrict__ resid, int K, u16* __restrict__ vTout) {
  constexpr int BK = 64;
  constexpr int NW = WM * WN;
  constexpr int FM = BM / WM / 16, FN = BN / WN / 16;
  constexpr int ABYTES = BM * BK * 2, BBYTES = BN * BK * 2;
  constexpr int ACH = ABYTES / 1024, BCH = BBYTES / 1024, NCH = ACH + BCH;
  extern __shared__ __align__(16) char smem[];

  const int tid = threadIdx.x, lane = tid & 63, wid = tid >> 6;
  const int brow = blockIdx.y * BM, bcol = blockIdx.x * BN;
  const long long kbase2 = (long long)blockIdx.z * (K / KS) * 2;

  const int nt = (K / KS) >> 6;
  const int widm = wid / WN, widn = wid % WN;
  const int rm0 = widm * (BM / WM), cn0 = widn * (BN / WN);

  f32x4 acc[FM][FN] = {};

  const int swq16 = (((lane & 7) ^ ((lane >> 3) & 7)) << 4);
  const int lrow8 = lane >> 3;

  auto stage = [&](int buf, int kt) {
    char* base = smem + buf * (ABYTES + BBYTES);
    const char* Ag = (const char*)A;
    const char* Bg = (const char*)Bt;
    long long kOff = kbase2 + (long long)kt * 128 + swq16;
#pragma unroll
    for (int ci = 0; ci < NCH / NW; ++ci) {
      int c = wid + ci * NW;
      if (c < ACH) {
        int r = c * 8 + lrow8;
        gld16(Ag + (long long)(brow + r) * (lda * 2) + kOff, base + c * 1024 + lane * 16);
      } else {
        int r = (c - ACH) * 8 + lrow8;
        gld16(Bg + (long long)(bcol + r) * (ldb * 2) + kOff,
              base + ABYTES + (c - ACH) * 1024 + lane * 16);
      }
    }
  };

  auto compute = [&](int buf) {
    char* baseA = smem + buf * (ABYTES + BBYTES);
    char* baseB = baseA + ABYTES;
#pragma unroll
    for (int ks = 0; ks < 2; ++ks) {
      short8 af[FM], bv[FN];
#pragma unroll
      for (int i = 0; i < FM; ++i) {
        int r = rm0 + i * 16 + (lane & 15);
        int cq = ((ks << 2) + (lane >> 4)) ^ (r & 7);
        af[i] = *(const short8*)(baseA + r * 128 + (cq << 4));
      }
#pragma unroll
      for (int j = 0; j < FN; ++j) {
        int r = cn0 + j * 16 + (lane & 15);
        int cq = ((ks << 2) + (lane >> 4)) ^ (r & 7);
        bv[j] = *(const short8*)(baseB + r * 128 + (cq << 4));
      }
#pragma unroll
      for (int i = 0; i < FM; ++i)
#pragma unroll
        for (int j = 0; j < FN; ++j)
          acc[i][j] = __builtin_amdgcn_mfma_f32_16x16x32_bf16(af[i], bv[j], acc[i][j], 0, 0, 0);
    }
  };

  if constexpr (STAGES == 3) {
    stage(0, 0);
    if (1 < nt) stage(1, 1);
    for (int t = 0; t < nt; ++t) {
      if (t + 1 < nt) asm volatile("s_waitcnt vmcnt(6)" ::: "memory");
      else            asm volatile("s_waitcnt vmcnt(0)" ::: "memory");
      __syncthreads();                    // publish tile t; compute(t-1) readers done
      if (t + 2 < nt) stage((t + 2) % 3, t + 2);
      compute(t % 3);
    }
    __syncthreads();                      // protect epilogue LDS reuse
  } else {
    stage(0, 0);
    __syncthreads();
    int cur = 0;
    for (int t = 0; t < nt; ++t) {
      if (t + 1 < nt) stage(cur ^ 1, t + 1);
      compute(cur);
      __syncthreads();
      cur ^= 1;
    }
  }

  if constexpr (EPI == EPI_QKV) {
    if (bcol >= 2 * DM) {
      // stash tile as [t_local][d_local] u16 with 130-u16 row pitch (bank spread)
      u16* st = (u16*)smem;
#pragma unroll
      for (int i = 0; i < FM; ++i)
#pragma unroll
        for (int j = 0; j < FN; ++j)
#pragma unroll
          for (int r = 0; r < 4; ++r) {
            int rl = rm0 + i * 16 + ((lane >> 4) << 2) + r;
            int cl = cn0 + j * 16 + (lane & 15);
            st[rl * 130 + cl] = f2b(acc[i][j][r] + bias[bcol + cl]);
          }
      __syncthreads();
      const int b = brow >> 10, t0b = brow & (TT - 1);
      const int h0 = (bcol - 2 * DM) >> 6;
      constexpr int NCHK = BM / 8;        // uint4 row-chunks (8 t-values each)
      constexpr int DPP = 256 / NCHK;     // d-lanes per pass
      const int sub = tid & (NCHK - 1);
#pragma unroll
      for (int pass = 0; pass < 128 / DPP; ++pass) {
        int d = pass * DPP + (tid / NCHK);
        u32 pk[4];
#pragma unroll
        for (int k2 = 0; k2 < 4; ++k2) {
          u16 lo = st[(sub * 8 + 2 * k2) * 130 + d];
          u16 hi = st[(sub * 8 + 2 * k2 + 1) * 130 + d];
          pk[k2] = (u32)lo | ((u32)hi << 16);
        }
        int head = h0 + (d >> 6), dd = d & 63;
        *(uint4*)(vTout + ((size_t)((b * NH + head) * HD + dd)) * TT + t0b + sub * 8) =
            make_uint4(pk[0], pk[1], pk[2], pk[3]);
      }
      return;
    }
  }

  const int r0 = brow + rm0 + ((lane >> 4) << 2);
  const int c0 = bcol + cn0 + (lane & 15);
#pragma unroll
  for (int i = 0; i < FM; ++i) {
#pragma unroll
    for (int j = 0; j < FN; ++j) {
#pragma unroll
      for (int r = 0; r < 4; ++r) {
        int row = r0 + i * 16 + r;
        int col = c0 + j * 16;
        float v = acc[i][j][r];
        if constexpr (EPI == EPI_BF16 || EPI == EPI_QKV) {
          ((u16*)C)[(size_t)row * ldc + col] = f2b(v + bias[col]);
        } else if constexpr (EPI == EPI_GELU) {
          ((u16*)C)[(size_t)row * ldc + col] = f2b(gelu_f(v + bias[col]));
        } else if constexpr (EPI == EPI_ADDF32) {
          size_t o = (size_t)row * ldc + col;
          resid[o] += v + bias[col];
        } else if constexpr (EPI == EPI_ATOMIC) {
          size_t o = (size_t)row * ldc + col;
          atomicAdd(&resid[o], v + (blockIdx.z == 0 ? bias[col] : 0.0f));
        } else {
          ((float*)C)[(size_t)row * ldc + col] = v + bias[col];
        }
      }
    }
  }
}

// ---------------- 8-phase 256x256 GEMM (T1..T5) — r2/r5-validated schedule ----------------
template <int EPI>
__global__ __launch_bounds__(512, 2) void gemm8(
    const u16* __restrict__ A, int lda, const u16* __restrict__ Bt, int ldb,
    const float* __restrict__ bias, void* __restrict__ C, int ldc, int K, int nby) {
  __shared__ __align__(16) char smem[2][2][32768];
  const int tid = threadIdx.x, lane = tid & 63;
  const int wid = tid >> 6, wm = wid >> 2, wn = wid & 3;

  const int nb = gridDim.x;
  const int q8 = nb >> 3, r8 = nb & 7;
  const int xcd = blockIdx.x & 7, lin = blockIdx.x >> 3;
  const int idx = (xcd < r8 ? xcd * (q8 + 1) : r8 * (q8 + 1) + (xcd - r8) * q8) + lin;
  const int brow = (idx % nby) * 256, bcol = (idx / nby) * 256;

  const int nt = K >> 6, niter = nt >> 1;

  const int srow = tid >> 3, sq = tid & 7;
  auto stage = [&](int buf, int isB, int half, int kt) {
    const u16* G = isB ? Bt : A;
    const int ld = isB ? ldb : lda;
    const int base = isB ? bcol : brow;
    char* L = &smem[buf][isB][half * 16384];
#pragma unroll
    for (int l = 0; l < 2; ++l) {
      int rl = half * 128 + l * 64 + srow;
      gld16((const char*)G + (size_t)(base + rl) * (ld * 2) + kt * 128 + ((sq ^ (rl & 7)) << 4),
            L + l * 8192 + tid * 16);
    }
  };

  short8 bfr[4][2], afr[2][2];
  f32x4 acc[8][4] = {};

  stage(0, 0, 0, 0); stage(0, 0, 1, 0);
  stage(0, 1, 0, 0); stage(0, 1, 1, 0);
  stage(1, 1, 0, 1); stage(1, 1, 1, 1);
  asm volatile("s_waitcnt vmcnt(0)" ::: "memory");
  __builtin_amdgcn_s_barrier();

  for (int i = 0; i < niter; ++i) {
    const bool full = (i + 1 < niter);
    const int t2 = 2 * i + 2, t3 = 2 * i + 3;
#pragma unroll
    for (int h = 0; h < 2; ++h) {
#pragma unroll
      for (int qd = 0; qd < 4; ++qd) {
        if (qd == 0) {
#pragma unroll
          for (int j = 0; j < 4; ++j)
#pragma unroll
            for (int ks = 0; ks < 2; ++ks) {
              int r = wn * 64 + j * 16 + (lane & 15);
              int q = ((ks << 2) + (lane >> 4)) ^ (r & 7);
              bfr[j][ks] = *(const short8*)&smem[h][1][r * 128 + q * 16];
            }
        }
#pragma unroll
        for (int f = 0; f < 2; ++f)
#pragma unroll
          for (int ks = 0; ks < 2; ++ks) {
            int r = wm * 128 + (qd * 2 + f) * 16 + (lane & 15);
            int q = ((ks << 2) + (lane >> 4)) ^ (r & 7);
            afr[f][ks] = *(const short8*)&smem[h][0][r * 128 + q * 16];
          }
        if (h == 0) {
          if (qd == 0) stage(1, 0, 0, 2 * i + 1);
          else if (qd == 1) stage(1, 0, 1, 2 * i + 1);
          else if (qd == 2) { if (full) stage(0, 1, 0, t2); }
          else              { if (full) stage(0, 1, 1, t2); }
        } else {
          if (qd == 0)      { if (full) stage(0, 0, 0, t2); }
          else if (qd == 1) { if (full) stage(0, 0, 1, t2); }
          else if (qd == 2) { if (full) stage(1, 1, 0, t3); }
          else              { if (full) stage(1, 1, 1, t3); }
        }
        if (qd == 3) {
          if (full) asm volatile("s_waitcnt vmcnt(4)" ::: "memory");
          else if (h == 0) asm volatile("s_waitcnt vmcnt(0)" ::: "memory");
        }
        __builtin_amdgcn_s_barrier();
        asm volatile("s_waitcnt lgkmcnt(0)" ::: "memory");
        __builtin_amdgcn_s_setprio(1);
#pragma unroll
        for (int f = 0; f < 2; ++f)
#pragma unroll
          for (int j = 0; j < 4; ++j)
#pragma unroll
            for (int ks = 0; ks < 2; ++ks)
              acc[qd * 2 + f][j] = __builtin_amdgcn_mfma_f32_16x16x32_bf16(
                  afr[f][ks], bfr[j][ks], acc[qd * 2 + f][j], 0, 0, 0);
        __builtin_amdgcn_s_setprio(0);
        __builtin_amdgcn_s_barrier();
      }
    }
  }

  const int r0 = brow + wm * 128 + ((lane >> 4) << 2);
  const int c0 = bcol + wn * 64 + (lane & 15);
#pragma unroll
  for (int fi = 0; fi < 8; ++fi) {
#pragma unroll
    for (int j = 0; j < 4; ++j) {
      int col = c0 + j * 16;
      float bv = bias[col];
#pragma unroll
      for (int r = 0; r < 4; ++r) {
        int row = r0 + fi * 16 + r;
        float v = acc[fi][j][r] + bv;
        if constexpr (EPI == EPI_F32)
          ((float*)C)[(size_t)row * ldc + col] = v;
        else if constexpr (EPI == EPI_GELU)
          ((u16*)C)[(size_t)row * ldc + col] = f2b(gelu_f(v));
        else
          ((u16*)C)[(size_t)row * ldc + col] = f2b(v);
      }
    }
  }
}

extern "C" void kernel_launch(void* const* d_in, const int* in_sizes, int n_in,
                              void* d_out, int out_size, void* d_ws, size_t ws_size,
                              hipStream_t stream) {
  (void)in_sizes; (void)n_in; (void)out_size;
  const int*   idx    = (const int*)d_in[0];
  const float* tok    = (const float*)d_in[1];
  const float* ln_e_g = (const float*)d_in[2];
  const float* ln_e_b = (const float*)d_in[3];
  const float* Wqkv   = (const float*)d_in[4];
  const float* bqkv   = (const float*)d_in[5];
  const float* Wo     = (const float*)d_in[6];
  const float* bo     = (const float*)d_in[7];
  const float* W1     = (const float*)d_in[8];
  const float* b1     = (const float*)d_in[9];
  const float* W2     = (const float*)d_in[10];
  const float* b2     = (const float*)d_in[11];
  const float* n1_w   = (const float*)d_in[12];
  const float* n2_w   = (const float*)d_in[13];
  const float* lnf_g  = (const float*)d_in[14];
  const float* lnf_b  = (const float*)d_in[15];
  const float* Wlm    = (const float*)d_in[16];
  const float* blm    = (const float*)d_in[17];
  float* out = (float*)d_out;

  char* w = (char*)d_ws;
  auto alloc = [&](size_t bytes) { char* p = w; w += (bytes + 255) & ~(size_t)255; return p; };
  float* x   = (float*)alloc((size_t)BT * DM * 4);
  u16* h     = (u16*)alloc((size_t)BT * DM * 2);
  u16* qkv   = (u16*)alloc((size_t)BT * 3 * DM * 2);
  u16* vT    = (u16*)alloc((size_t)BBATCH * NH * HD * TT * 2);
  u16* y     = (u16*)alloc((size_t)BT * DM * 2);
  u16* act   = (u16*)alloc((size_t)BT * DFF * 2);
  u16* xf    = (u16*)alloc((size_t)BT * DM * 2);
  u16* WqkvT = (u16*)alloc((size_t)3 * DM * DM * 2);
  u16* WoT   = (u16*)alloc((size_t)DM * DM * 2);
  u16* W1T   = (u16*)alloc((size_t)DFF * DM * 2);
  u16* W2T   = (u16*)alloc((size_t)DM * DFF * 2);
  u16* WlmT  = (u16*)alloc((size_t)NV * DM * 2);
  if ((size_t)(w - (char*)d_ws) > ws_size) return;

  // weights transpose + embedding LayerNorm fused in one launch
  wt_embed_all<<<22144 + BT, 256, 0, stream>>>(Wqkv, Wo, W1, W2, Wlm,
                                               WqkvT, WoT, W1T, W2T, WlmT,
                                               idx, tok, ln_e_g, ln_e_b, x);

  constexpr int SM128 = 2 * (128 * 64 * 2 + 128 * 64 * 2);  // 65536
  constexpr int SM64_3 = 3 * (128 * 64 * 2 + 64 * 64 * 2);  // 73728 (3-deep Wo)
  constexpr int SMQ3   = 3 * (64 * 64 * 2 + 128 * 64 * 2);  // 73728 (3-deep QKV)

  for (int l = 0; l < NL; ++l) {
    rmsnorm_k<<<BT, 256, 0, stream>>>(x, n1_w, h);
    gemm_bt<64, 128, 2, 2, EPI_QKV, 1, 3><<<dim3(3 * DM / 128, BT / 64), 256, SMQ3, stream>>>(
        h, DM, WqkvT, DM, bqkv, qkv, 3 * DM, nullptr, DM, vT);
    attn_k<<<512, 256, 0, stream>>>(qkv, vT, y);
    gemm_bt<128, 64, 4, 1, EPI_ADDF32, 1, 3><<<dim3(DM / 64, BT / 128), 256, SM64_3, stream>>>(
        y, DM, WoT, DM, bo, nullptr, DM, x, DM, nullptr);
    rmsnorm_k<<<BT, 256, 0, stream>>>(x, n2_w, h);
    gemm_bt<128, 128, 2, 2, EPI_GELU><<<dim3(DFF / 128, BT / 128), 256, SM128, stream>>>(
        h, DM, W1T, DM, b1, act, DFF, nullptr, DM, nullptr);
    gemm_bt<128, 128, 2, 2, EPI_ATOMIC, 2><<<dim3(DM / 128, BT / 128, 2), 256, SM128, stream>>>(
        act, DFF, W2T, DFF, b2, nullptr, DM, x, DFF, nullptr);
  }

  final_ln_k<<<BT, 256, 0, stream>>>(x, lnf_g, lnf_b, xf);
  gemm8<EPI_F32><<<dim3((NV / 256) * (BT / 256)), 512, 0, stream>>>(
      xf, DM, WlmT, DM, blm, out, NV, DM, BT / 256);
}

// Round 15
// 814.463 us; speedup vs baseline: 1.0189x; 1.0189x over previous
//
#include <hip/hip_runtime.h>
#include <stdint.h>

#define DEVI __device__ __forceinline__

typedef __attribute__((ext_vector_type(8))) short short8;
typedef __attribute__((ext_vector_type(4))) float f32x4;
typedef unsigned short u16;
typedef unsigned int u32;

typedef const __attribute__((address_space(1))) void* gas_ptr;
typedef __attribute__((address_space(3))) void* las_ptr;

constexpr int BBATCH = 2;
constexpr int TT  = 1024;
constexpr int BT  = BBATCH * TT;   // 2048 tokens
constexpr int DM  = 1024;
constexpr int NH  = 16;
constexpr int HD  = 64;
constexpr int DFF = 4096;
constexpr int NV  = 32000;
constexpr int NL  = 4;

DEVI u16 f2b(float f) {
  u32 u = __builtin_bit_cast(u32, f);
  u = (u + 0x7fffu + ((u >> 16) & 1u)) >> 16;
  return (u16)u;
}
DEVI float b2f(u16 h) { return __builtin_bit_cast(float, (u32)h << 16); }

DEVI void gld16(const void* g, void* l) {
  __builtin_amdgcn_global_load_lds((gas_ptr)g, (las_ptr)l, 16, 0, 0);
}

DEVI float wave_sum(float v) {
#pragma unroll
  for (int off = 32; off; off >>= 1) v += __shfl_xor(v, off);
  return v;
}
DEVI float block_sum(float v, float* sb) {
  v = wave_sum(v);
  int lane = threadIdx.x & 63, wid = threadIdx.x >> 6;
  __syncthreads();
  if (lane == 0) sb[wid] = v;
  __syncthreads();
  return sb[0] + sb[1] + sb[2] + sb[3];
}

DEVI float gelu_f(float x) {
  float u = 0.7978845608028654f * (x + 0.044715f * x * x * x);
  float e = __expf(2.0f * u);            // gelu = x * sigmoid(2u)
  return x * (1.0f - 1.0f / (e + 1.0f));
}

// ---------------- fused weight transpose+convert: f32 [K][N] -> bf16 [N][K] ----------------
// 64(k) x 32(n) tiles; writes packed u32 (2 u16) -> 128B segments both directions.
__global__ __launch_bounds__(256) void wt_transpose_all(
    const float* __restrict__ Wqkv, const float* __restrict__ Wo,
    const float* __restrict__ W1, const float* __restrict__ W2,
    const float* __restrict__ Wlm,
    u16* __restrict__ WqkvT, u16* __restrict__ WoT, u16* __restrict__ W1T,
    u16* __restrict__ W2T, u16* __restrict__ WlmT) {
  __shared__ float t[64][33];
  int bid = blockIdx.x;
  const float* in; u16* out; int K, N, tt;
  if (bid < 1536)      { in = Wqkv; out = WqkvT; K = 1024; N = 3072;  tt = bid; }
  else if (bid < 2048) { in = Wo;   out = WoT;   K = 1024; N = 1024;  tt = bid - 1536; }
  else if (bid < 4096) { in = W1;   out = W1T;   K = 1024; N = 4096;  tt = bid - 2048; }
  else if (bid < 6144) { in = W2;   out = W2T;   K = 4096; N = 1024;  tt = bid - 4096; }
  else                 { in = Wlm;  out = WlmT;  K = 1024; N = 32000; tt = bid - 6144; }
  int nx = N >> 5;
  int n0 = (tt % nx) * 32, k0 = (tt / nx) * 64;
  int tx = threadIdx.x & 31, ty = threadIdx.x >> 5;   // ty 0..7
#pragma unroll
  for (int i = 0; i < 8; ++i)
    t[ty + 8 * i][tx] = in[(size_t)(k0 + ty + 8 * i) * N + n0 + tx];
  __syncthreads();
#pragma unroll
  for (int i = 0; i < 4; ++i) {
    int r = ty + 8 * i;                               // n-local 0..31
    u32 pk = (u32)f2b(t[2 * tx][r]) | ((u32)f2b(t[2 * tx + 1][r]) << 16);
    *(u32*)(out + (size_t)(n0 + r) * K + k0 + 2 * tx) = pk;
  }
}

// ---------------- embedding gather + LayerNorm -> x f32 ----------------
__global__ __launch_bounds__(256) void embed_ln_k(const int* __restrict__ idx,
                                                  const float* __restrict__ tok,
                                                  const float* __restrict__ g,
                                                  const float* __restrict__ b,
                                                  float* __restrict__ x) {
  __shared__ float sb[4];
  int row = blockIdx.x, tid = threadIdx.x;
  float4 v = ((const float4*)(tok + (size_t)idx[row] * DM))[tid];
  float s = block_sum(v.x + v.y + v.z + v.w, sb);
  float m = s * (1.0f / DM);
  float dx = v.x - m, dy = v.y - m, dz = v.z - m, dw = v.w - m;
  float q = block_sum(dx * dx + dy * dy + dz * dz + dw * dw, sb);
  float rs = rsqrtf(q * (1.0f / DM) + 1e-5f);
  float4 gg = ((const float4*)g)[tid];
  float4 bb = ((const float4*)b)[tid];
  float4 o = make_float4(dx * rs * gg.x + bb.x, dy * rs * gg.y + bb.y,
                         dz * rs * gg.z + bb.z, dw * rs * gg.w + bb.w);
  ((float4*)(x + (size_t)row * DM))[tid] = o;
}

// ---------------- final LayerNorm -> bf16 ----------------
__global__ __launch_bounds__(256) void final_ln_k(const float* __restrict__ x,
                                                  const float* __restrict__ g,
                                                  const float* __restrict__ b,
                                                  u16* __restrict__ xf) {
  __shared__ float sb[4];
  int row = blockIdx.x, tid = threadIdx.x;
  float4 v = ((const float4*)(x + (size_t)row * DM))[tid];
  float s = block_sum(v.x + v.y + v.z + v.w, sb);
  float m = s * (1.0f / DM);
  float dx = v.x - m, dy = v.y - m, dz = v.z - m, dw = v.w - m;
  float q = block_sum(dx * dx + dy * dy + dz * dz + dw * dw, sb);
  float rs = rsqrtf(q * (1.0f / DM) + 1e-5f);
  float4 gg = ((const float4*)g)[tid];
  float4 bb = ((const float4*)b)[tid];
  u32 lo = (u32)f2b(dx * rs * gg.x + bb.x) | ((u32)f2b(dy * rs * gg.y + bb.y) << 16);
  u32 hi = (u32)f2b(dz * rs * gg.z + bb.z) | ((u32)f2b(dw * rs * gg.w + bb.w) << 16);
  ((uint2*)(xf + (size_t)row * DM))[tid] = make_uint2(lo, hi);
}

// ---------------- RMSNorm f32 -> bf16 ----------------
__global__ __launch_bounds__(256) void rmsnorm_k(const float* __restrict__ x,
                                                 const float* __restrict__ w,
                                                 u16* __restrict__ h) {
  __shared__ float sb[4];
  int row = blockIdx.x, tid = threadIdx.x;
  float4 v = ((const float4*)(x + (size_t)row * DM))[tid];
  float q = block_sum(v.x * v.x + v.y * v.y + v.z * v.z + v.w * v.w, sb);
  float rs = rsqrtf(q * (1.0f / DM) + 1.1920928955078125e-7f);
  float4 ww = ((const float4*)w)[tid];
  u32 lo = (u32)f2b(v.x * rs * ww.x) | ((u32)f2b(v.y * rs * ww.y) << 16);
  u32 hi = (u32)f2b(v.z * rs * ww.z) | ((u32)f2b(v.w * rs * ww.w) << 16);
  ((uint2*)(h + (size_t)row * DM))[tid] = make_uint2(lo, hi);
}

// ---------------- fused flash attention, QBLK=64, double-buffered KV (r13-validated) ----------------
__global__ __launch_bounds__(256) void attn_k(const u16* __restrict__ qkv,
                                              const u16* __restrict__ vT,
                                              u16* __restrict__ y) {
  __shared__ __align__(16) char sP[16384];      // Q [64][128B] swz8, then P [64][256B] swz16
  __shared__ __align__(16) char sK[2][16384];   // K tile [128][128B] swz8
  __shared__ __align__(16) char sV[2][16384];   // Vt tile [64][256B] swz16
  const int tid = threadIdx.x, lane = tid & 63, wid = tid >> 6;
  const int bid = blockIdx.x;
  const int sl = (bid + (bid >> 8)) & 15;
  const int qt = (sl & 1) ? (sl >> 1) : (15 - (sl >> 1));   // balanced pairing
  const int bh = (bid >> 4) & 31, b = bh >> 4, h = bh & 15;
  const int nt = (qt >> 1) + 1;                             // kv tiles (128 wide)
  const float slope = exp2f(-0.5f * (float)(h + 1));

  const char* Qb = (const char*)(qkv + (size_t)b * TT * 3 * DM + h * HD);
  const char* Kb = (const char*)(qkv + (size_t)b * TT * 3 * DM + DM + h * HD);
  const char* Vb = (const char*)(vT + (size_t)bh * HD * TT);

#pragma unroll
  for (int ci = 0; ci < 2; ++ci) {
    int c = wid * 2 + ci;
    int r = c * 8 + (lane >> 3);
    int q = (lane & 7) ^ (r & 7);
    gld16(Qb + (size_t)(qt * 64 + r) * 6144 + q * 16, sP + c * 1024 + lane * 16);
  }

  auto stageKV = [&](int buf, int kt) {
    int kv0 = kt * 128;
#pragma unroll
    for (int ci = 0; ci < 4; ++ci) {            // K: [128][128B]
      int c = wid * 4 + ci;
      int r = c * 8 + (lane >> 3);
      int q = (lane & 7) ^ (r & 7);
      gld16(Kb + (size_t)(kv0 + r) * 6144 + q * 16, sK[buf] + c * 1024 + lane * 16);
    }
#pragma unroll
    for (int ci = 0; ci < 4; ++ci) {            // Vt: [64][256B]
      int c = wid * 4 + ci;
      int d = c * 4 + (lane >> 4);
      int q = (lane & 15) ^ (d & 15);
      gld16(Vb + (size_t)d * 2048 + (size_t)kv0 * 2 + q * 16, sV[buf] + c * 1024 + lane * 16);
    }
  };
  stageKV(0, 0);
  asm volatile("s_waitcnt vmcnt(8)" ::: "memory");   // Q's 2 loads (oldest) done

  short8 qf[2];
#pragma unroll
  for (int ks = 0; ks < 2; ++ks) {
    int r = wid * 16 + (lane & 15);
    int q = ((ks << 2) + (lane >> 4)) ^ (r & 7);
    qf[ks] = *(const short8*)(sP + r * 128 + q * 16);
  }

  f32x4 Y[4] = {};
  float m_r[4], l_r[4];
#pragma unroll
  for (int r = 0; r < 4; ++r) { m_r[r] = -3e38f; l_r[r] = 0.0f; }

  for (int kt = 0; kt < nt; ++kt) {
    const int cur = kt & 1;
    if (kt + 1 < nt) {
      stageKV(cur ^ 1, kt + 1);                      // prefetch next tile
      asm volatile("s_waitcnt vmcnt(8)" ::: "memory");  // wait current tile only
    } else {
      asm volatile("s_waitcnt vmcnt(0)" ::: "memory");
    }
    __syncthreads();   // publish tile kt (and: Q regs loaded before any P write)

    // QK^T
    f32x4 s[8] = {};
    __builtin_amdgcn_s_setprio(1);
#pragma unroll
    for (int ks = 0; ks < 2; ++ks) {
      short8 kf[8];
#pragma unroll
      for (int j = 0; j < 8; ++j) {
        int r = j * 16 + (lane & 15);
        int q = ((ks << 2) + (lane >> 4)) ^ (r & 7);
        kf[j] = *(const short8*)(sK[cur] + r * 128 + q * 16);
      }
#pragma unroll
      for (int j = 0; j < 8; ++j)
        s[j] = __builtin_amdgcn_mfma_f32_16x16x32_bf16(qf[ks], kf[j], s[j], 0, 0, 0);
    }
    __builtin_amdgcn_s_setprio(0);

    // scale + row-invariant ALiBi (+slope*kcol) + causal mask + online softmax
    const int kv0 = kt * 128;
    const int qbase = qt * 64 + wid * 16 + ((lane >> 4) << 2);
    float colb[8];
#pragma unroll
    for (int j = 0; j < 8; ++j)
      colb[j] = slope * (float)(kv0 + j * 16 + (lane & 15));
    float rowmax[4] = {-3e38f, -3e38f, -3e38f, -3e38f};
    if (kv0 + 127 <= qt * 64) {
      // fully-unmasked tile (block-uniform): no causal select needed
#pragma unroll
      for (int j = 0; j < 8; ++j)
#pragma unroll
        for (int r = 0; r < 4; ++r) {
          float v = fmaf(s[j][r], 0.125f, colb[j]);
          s[j][r] = v;
          rowmax[r] = fmaxf(rowmax[r], v);
        }
    } else {
#pragma unroll
      for (int j = 0; j < 8; ++j) {
        int kcol = kv0 + j * 16 + (lane & 15);
#pragma unroll
        for (int r = 0; r < 4; ++r) {
          float v = (kcol <= qbase + r) ? fmaf(s[j][r], 0.125f, colb[j]) : -3e38f;
          s[j][r] = v;
          rowmax[r] = fmaxf(rowmax[r], v);
        }
      }
    }
#pragma unroll
    for (int r = 0; r < 4; ++r) {
      rowmax[r] = fmaxf(rowmax[r], __shfl_xor(rowmax[r], 1));
      rowmax[r] = fmaxf(rowmax[r], __shfl_xor(rowmax[r], 2));
      rowmax[r] = fmaxf(rowmax[r], __shfl_xor(rowmax[r], 4));
      rowmax[r] = fmaxf(rowmax[r], __shfl_xor(rowmax[r], 8));
      float mn = fmaxf(m_r[r], rowmax[r]);
      float al = __expf(m_r[r] - mn);
      m_r[r] = mn;
      l_r[r] *= al;
#pragma unroll
      for (int j = 0; j < 4; ++j) Y[j][r] *= al;
    }
    float rs[4] = {0.0f, 0.0f, 0.0f, 0.0f};
#pragma unroll
    for (int j = 0; j < 8; ++j)
#pragma unroll
      for (int r = 0; r < 4; ++r) {
        float p = __expf(s[j][r] - m_r[r]);
        s[j][r] = p;
        rs[r] += p;
      }
#pragma unroll
    for (int r = 0; r < 4; ++r) {
      rs[r] += __shfl_xor(rs[r], 1);
      rs[r] += __shfl_xor(rs[r], 2);
      rs[r] += __shfl_xor(rs[r], 4);
      rs[r] += __shfl_xor(rs[r], 8);
      l_r[r] += rs[r];
    }
    // write P (bf16) to own sP rows, swz16 over 256B rows
#pragma unroll
    for (int j = 0; j < 8; ++j)
#pragma unroll
      for (int r = 0; r < 4; ++r) {
        int rl = wid * 16 + ((lane >> 4) << 2) + r;
        int c = j * 16 + (lane & 15);
        int g = c >> 3;
        *(u16*)(sP + rl * 256 + ((g ^ (rl & 15)) << 4) + (c & 7) * 2) = f2b(s[j][r]);
      }

    // PV: Y += P(own rows) * Vt
    __builtin_amdgcn_s_setprio(1);
#pragma unroll
    for (int ks = 0; ks < 4; ++ks) {
      short8 pf, vf[4];
      {
        int r = wid * 16 + (lane & 15);
        int q = ((ks << 2) + (lane >> 4)) ^ (r & 15);
        pf = *(const short8*)(sP + r * 256 + (q << 4));
      }
#pragma unroll
      for (int j = 0; j < 4; ++j) {
        int d = j * 16 + (lane & 15);
        int q = ((ks << 2) + (lane >> 4)) ^ (d & 15);
        vf[j] = *(const short8*)(sV[cur] + d * 256 + (q << 4));
      }
#pragma unroll
      for (int j = 0; j < 4; ++j)
        Y[j] = __builtin_amdgcn_mfma_f32_16x16x32_bf16(pf, vf[j], Y[j], 0, 0, 0);
    }
    __builtin_amdgcn_s_setprio(0);
    __syncthreads();   // all waves done reading bufs[cur] + sP before next overwrite
  }

  // epilogue: y[b, qrow, h*64 + d] = Y / l
#pragma unroll
  for (int r = 0; r < 4; ++r) {
    float inv = 1.0f / l_r[r];
    int qrow = qt * 64 + wid * 16 + ((lane >> 4) << 2) + r;
    u16* yp = y + (size_t)(b * TT + qrow) * DM + h * HD;
#pragma unroll
    for (int j = 0; j < 4; ++j)
      yp[j * 16 + (lane & 15)] = f2b(Y[j][r] * inv);
  }
}

// ---------------- GEMM epilogue variants ----------------
enum { EPI_BF16 = 0, EPI_GELU = 1, EPI_ADDF32 = 2, EPI_F32 = 3, EPI_ATOMIC = 4, EPI_QKV = 5 };

// ---------------- 2-phase 128-tile GEMM (validated r1) + split-K + fused V-transpose ----------------
// EPI_QKV transpose epilogue is BM-generic: NCHK=BM/8 row-chunks of 8 t-values
// (uint4), 256/NCHK d-lanes per pass.
template <int BM, int BN, int WM, int WN, int EPI, int KS = 1>
__global__ __launch_bounds__(256, 2) void gemm_bt(
    const u16* __restrict__ A, int lda, const u16* __restrict__ Bt, int ldb,
    const float* __restrict__ bias, void* __restrict__ C, int ldc,
    float* __restrict__ resid, int K, u16* __restrict__ vTout) {
  constexpr int BK = 64;
  constexpr int NW = WM * WN;
  constexpr int FM = BM / WM / 16, FN = BN / WN / 16;
  constexpr int ABYTES = BM * BK * 2, BBYTES = BN * BK * 2;
  constexpr int ACH = ABYTES / 1024, BCH = BBYTES / 1024, NCH = ACH + BCH;
  extern __shared__ __align__(16) char smem[];

  const int tid = threadIdx.x, lane = tid & 63, wid = tid >> 6;
  const int brow = blockIdx.y * BM, bcol = blockIdx.x * BN;
  const long long kbase2 = (long long)blockIdx.z * (K / KS) * 2;

  const int nt = (K / KS) >> 6;
  const int widm = wid / WN, widn = wid % WN;
  const int rm0 = widm * (BM / WM), cn0 = widn * (BN / WN);

  f32x4 acc[FM][FN] = {};

  const int swq16 = (((lane & 7) ^ ((lane >> 3) & 7)) << 4);
  const int lrow8 = lane >> 3;

  auto stage = [&](int buf, int kt) {
    char* base = smem + buf * (ABYTES + BBYTES);
    const char* Ag = (const char*)A;
    const char* Bg = (const char*)Bt;
    long long kOff = kbase2 + (long long)kt * 128 + swq16;
#pragma unroll
    for (int ci = 0; ci < NCH / NW; ++ci) {
      int c = wid + ci * NW;
      if (c < ACH) {
        int r = c * 8 + lrow8;
        gld16(Ag + (long long)(brow + r) * (lda * 2) + kOff, base + c * 1024 + lane * 16);
      } else {
        int r = (c - ACH) * 8 + lrow8;
        gld16(Bg + (long long)(bcol + r) * (ldb * 2) + kOff,
              base + ABYTES + (c - ACH) * 1024 + lane * 16);
      }
    }
  };

  auto compute = [&](int buf) {
    char* baseA = smem + buf * (ABYTES + BBYTES);
    char* baseB = baseA + ABYTES;
#pragma unroll
    for (int ks = 0; ks < 2; ++ks) {
      short8 af[FM], bv[FN];
#pragma unroll
      for (int i = 0; i < FM; ++i) {
        int r = rm0 + i * 16 + (lane & 15);
        int cq = ((ks << 2) + (lane >> 4)) ^ (r & 7);
        af[i] = *(const short8*)(baseA + r * 128 + (cq << 4));
      }
#pragma unroll
      for (int j = 0; j < FN; ++j) {
        int r = cn0 + j * 16 + (lane & 15);
        int cq = ((ks << 2) + (lane >> 4)) ^ (r & 7);
        bv[j] = *(const short8*)(baseB + r * 128 + (cq << 4));
      }
#pragma unroll
      for (int i = 0; i < FM; ++i)
#pragma unroll
        for (int j = 0; j < FN; ++j)
          acc[i][j] = __builtin_amdgcn_mfma_f32_16x16x32_bf16(af[i], bv[j], acc[i][j], 0, 0, 0);
    }
  };

  stage(0, 0);
  __syncthreads();
  int cur = 0;
  for (int t = 0; t < nt; ++t) {
    if (t + 1 < nt) stage(cur ^ 1, t + 1);
    compute(cur);
    __syncthreads();
    cur ^= 1;
  }

  if constexpr (EPI == EPI_QKV) {
    if (bcol >= 2 * DM) {
      // stash tile as [t_local][d_local] u16 with 130-u16 row pitch (bank spread)
      u16* st = (u16*)smem;
#pragma unroll
      for (int i = 0; i < FM; ++i)
#pragma unroll
        for (int j = 0; j < FN; ++j)
#pragma unroll
          for (int r = 0; r < 4; ++r) {
            int rl = rm0 + i * 16 + ((lane >> 4) << 2) + r;
            int cl = cn0 + j * 16 + (lane & 15);
            st[rl * 130 + cl] = f2b(acc[i][j][r] + bias[bcol + cl]);
          }
      __syncthreads();
      const int b = brow >> 10, t0b = brow & (TT - 1);
      const int h0 = (bcol - 2 * DM) >> 6;
      constexpr int NCHK = BM / 8;        // uint4 row-chunks (8 t-values each)
      constexpr int DPP = 256 / NCHK;     // d-lanes per pass
      const int sub = tid & (NCHK - 1);
#pragma unroll
      for (int pass = 0; pass < 128 / DPP; ++pass) {
        int d = pass * DPP + (tid / NCHK);
        u32 pk[4];
#pragma unroll
        for (int k2 = 0; k2 < 4; ++k2) {
          u16 lo = st[(sub * 8 + 2 * k2) * 130 + d];
          u16 hi = st[(sub * 8 + 2 * k2 + 1) * 130 + d];
          pk[k2] = (u32)lo | ((u32)hi << 16);
        }
        int head = h0 + (d >> 6), dd = d & 63;
        *(uint4*)(vTout + ((size_t)((b * NH + head) * HD + dd)) * TT + t0b + sub * 8) =
            make_uint4(pk[0], pk[1], pk[2], pk[3]);
      }
      return;
    }
  }

  const int r0 = brow + rm0 + ((lane >> 4) << 2);
  const int c0 = bcol + cn0 + (lane & 15);
#pragma unroll
  for (int i = 0; i < FM; ++i) {
#pragma unroll
    for (int j = 0; j < FN; ++j) {
#pragma unroll
      for (int r = 0; r < 4; ++r) {
        int row = r0 + i * 16 + r;
        int col = c0 + j * 16;
        float v = acc[i][j][r];
        if constexpr (EPI == EPI_BF16 || EPI == EPI_QKV) {
          ((u16*)C)[(size_t)row * ldc + col] = f2b(v + bias[col]);
        } else if constexpr (EPI == EPI_GELU) {
          ((u16*)C)[(size_t)row * ldc + col] = f2b(gelu_f(v + bias[col]));
        } else if constexpr (EPI == EPI_ADDF32) {
          size_t o = (size_t)row * ldc + col;
          resid[o] += v + bias[col];
        } else if constexpr (EPI == EPI_ATOMIC) {
          size_t o = (size_t)row * ldc + col;
          atomicAdd(&resid[o], v + (blockIdx.z == 0 ? bias[col] : 0.0f));
        } else {
          ((float*)C)[(size_t)row * ldc + col] = v + bias[col];
        }
      }
    }
  }
}

// ---------------- 8-phase 256x256 GEMM (T1..T5) — r2/r5-validated schedule ----------------
template <int EPI>
__global__ __launch_bounds__(512, 2) void gemm8(
    const u16* __restrict__ A, int lda, const u16* __restrict__ Bt, int ldb,
    const float* __restrict__ bias, void* __restrict__ C, int ldc, int K, int nby) {
  __shared__ __align__(16) char smem[2][2][32768];
  const int tid = threadIdx.x, lane = tid & 63;
  const int wid = tid >> 6, wm = wid >> 2, wn = wid & 3;

  const int nb = gridDim.x;
  const int q8 = nb >> 3, r8 = nb & 7;
  const int xcd = blockIdx.x & 7, lin = blockIdx.x >> 3;
  const int idx = (xcd < r8 ? xcd * (q8 + 1) : r8 * (q8 + 1) + (xcd - r8) * q8) + lin;
  const int brow = (idx % nby) * 256, bcol = (idx / nby) * 256;

  const int nt = K >> 6, niter = nt >> 1;

  const int srow = tid >> 3, sq = tid & 7;
  auto stage = [&](int buf, int isB, int half, int kt) {
    const u16* G = isB ? Bt : A;
    const int ld = isB ? ldb : lda;
    const int base = isB ? bcol : brow;
    char* L = &smem[buf][isB][half * 16384];
#pragma unroll
    for (int l = 0; l < 2; ++l) {
      int rl = half * 128 + l * 64 + srow;
      gld16((const char*)G + (size_t)(base + rl) * (ld * 2) + kt * 128 + ((sq ^ (rl & 7)) << 4),
            L + l * 8192 + tid * 16);
    }
  };

  short8 bfr[4][2], afr[2][2];
  f32x4 acc[8][4] = {};

  stage(0, 0, 0, 0); stage(0, 0, 1, 0);
  stage(0, 1, 0, 0); stage(0, 1, 1, 0);
  stage(1, 1, 0, 1); stage(1, 1, 1, 1);
  asm volatile("s_waitcnt vmcnt(0)" ::: "memory");
  __builtin_amdgcn_s_barrier();

  for (int i = 0; i < niter; ++i) {
    const bool full = (i + 1 < niter);
    const int t2 = 2 * i + 2, t3 = 2 * i + 3;
#pragma unroll
    for (int h = 0; h < 2; ++h) {
#pragma unroll
      for (int qd = 0; qd < 4; ++qd) {
        if (qd == 0) {
#pragma unroll
          for (int j = 0; j < 4; ++j)
#pragma unroll
            for (int ks = 0; ks < 2; ++ks) {
              int r = wn * 64 + j * 16 + (lane & 15);
              int q = ((ks << 2) + (lane >> 4)) ^ (r & 7);
              bfr[j][ks] = *(const short8*)&smem[h][1][r * 128 + q * 16];
            }
        }
#pragma unroll
        for (int f = 0; f < 2; ++f)
#pragma unroll
          for (int ks = 0; ks < 2; ++ks) {
            int r = wm * 128 + (qd * 2 + f) * 16 + (lane & 15);
            int q = ((ks << 2) + (lane >> 4)) ^ (r & 7);
            afr[f][ks] = *(const short8*)&smem[h][0][r * 128 + q * 16];
          }
        if (h == 0) {
          if (qd == 0) stage(1, 0, 0, 2 * i + 1);
          else if (qd == 1) stage(1, 0, 1, 2 * i + 1);
          else if (qd == 2) { if (full) stage(0, 1, 0, t2); }
          else              { if (full) stage(0, 1, 1, t2); }
        } else {
          if (qd == 0)      { if (full) stage(0, 0, 0, t2); }
          else if (qd == 1) { if (full) stage(0, 0, 1, t2); }
          else if (qd == 2) { if (full) stage(1, 1, 0, t3); }
          else              { if (full) stage(1, 1, 1, t3); }
        }
        if (qd == 3) {
          if (full) asm volatile("s_waitcnt vmcnt(4)" ::: "memory");
          else if (h == 0) asm volatile("s_waitcnt vmcnt(0)" ::: "memory");
        }
        __builtin_amdgcn_s_barrier();
        asm volatile("s_waitcnt lgkmcnt(0)" ::: "memory");
        __builtin_amdgcn_s_setprio(1);
#pragma unroll
        for (int f = 0; f < 2; ++f)
#pragma unroll
          for (int j = 0; j < 4; ++j)
#pragma unroll
            for (int ks = 0; ks < 2; ++ks)
              acc[qd * 2 + f][j] = __builtin_amdgcn_mfma_f32_16x16x32_bf16(
                  afr[f][ks], bfr[j][ks], acc[qd * 2 + f][j], 0, 0, 0);
        __builtin_amdgcn_s_setprio(0);
        __builtin_amdgcn_s_barrier();
      }
    }
  }

  const int r0 = brow + wm * 128 + ((lane >> 4) << 2);
  const int c0 = bcol + wn * 64 + (lane & 15);
#pragma unroll
  for (int fi = 0; fi < 8; ++fi) {
#pragma unroll
    for (int j = 0; j < 4; ++j) {
      int col = c0 + j * 16;
      float bv = bias[col];
#pragma unroll
      for (int r = 0; r < 4; ++r) {
        int row = r0 + fi * 16 + r;
        float v = acc[fi][j][r] + bv;
        if constexpr (EPI == EPI_F32)
          ((float*)C)[(size_t)row * ldc + col] = v;
        else if constexpr (EPI == EPI_GELU)
          ((u16*)C)[(size_t)row * ldc + col] = f2b(gelu_f(v));
        else
          ((u16*)C)[(size_t)row * ldc + col] = f2b(v);
      }
    }
  }
}

extern "C" void kernel_launch(void* const* d_in, const int* in_sizes, int n_in,
                              void* d_out, int out_size, void* d_ws, size_t ws_size,
                              hipStream_t stream) {
  (void)in_sizes; (void)n_in; (void)out_size;
  const int*   idx    = (const int*)d_in[0];
  const float* tok    = (const float*)d_in[1];
  const float* ln_e_g = (const float*)d_in[2];
  const float* ln_e_b = (const float*)d_in[3];
  const float* Wqkv   = (const float*)d_in[4];
  const float* bqkv   = (const float*)d_in[5];
  const float* Wo     = (const float*)d_in[6];
  const float* bo     = (const float*)d_in[7];
  const float* W1     = (const float*)d_in[8];
  const float* b1     = (const float*)d_in[9];
  const float* W2     = (const float*)d_in[10];
  const float* b2     = (const float*)d_in[11];
  const float* n1_w   = (const float*)d_in[12];
  const float* n2_w   = (const float*)d_in[13];
  const float* lnf_g  = (const float*)d_in[14];
  const float* lnf_b  = (const float*)d_in[15];
  const float* Wlm    = (const float*)d_in[16];
  const float* blm    = (const float*)d_in[17];
  float* out = (float*)d_out;

  char* w = (char*)d_ws;
  auto alloc = [&](size_t bytes) { char* p = w; w += (bytes + 255) & ~(size_t)255; return p; };
  float* x   = (float*)alloc((size_t)BT * DM * 4);
  u16* h     = (u16*)alloc((size_t)BT * DM * 2);
  u16* qkv   = (u16*)alloc((size_t)BT * 3 * DM * 2);
  u16* vT    = (u16*)alloc((size_t)BBATCH * NH * HD * TT * 2);
  u16* y     = (u16*)alloc((size_t)BT * DM * 2);
  u16* act   = (u16*)alloc((size_t)BT * DFF * 2);
  u16* xf    = (u16*)alloc((size_t)BT * DM * 2);
  u16* WqkvT = (u16*)alloc((size_t)3 * DM * DM * 2);
  u16* WoT   = (u16*)alloc((size_t)DM * DM * 2);
  u16* W1T   = (u16*)alloc((size_t)DFF * DM * 2);
  u16* W2T   = (u16*)alloc((size_t)DM * DFF * 2);
  u16* WlmT  = (u16*)alloc((size_t)NV * DM * 2);
  if ((size_t)(w - (char*)d_ws) > ws_size) return;

  wt_transpose_all<<<22144, 256, 0, stream>>>(Wqkv, Wo, W1, W2, Wlm,
                                              WqkvT, WoT, W1T, W2T, WlmT);

  embed_ln_k<<<BT, 256, 0, stream>>>(idx, tok, ln_e_g, ln_e_b, x);

  constexpr int SM128 = 2 * (128 * 64 * 2 + 128 * 64 * 2);  // 65536
  constexpr int SM64  = 2 * (128 * 64 * 2 + 64 * 64 * 2);   // 49152
  constexpr int SMQ   = 2 * (64 * 64 * 2 + 128 * 64 * 2);   // 49152

  for (int l = 0; l < NL; ++l) {
    rmsnorm_k<<<BT, 256, 0, stream>>>(x, n1_w, h);
    gemm_bt<64, 128, 2, 2, EPI_QKV><<<dim3(3 * DM / 128, BT / 64), 256, SMQ, stream>>>(
        h, DM, WqkvT, DM, bqkv, qkv, 3 * DM, nullptr, DM, vT);
    attn_k<<<512, 256, 0, stream>>>(qkv, vT, y);
    // Wo: BN=64, KS=1 -> grid (16,16)=256 blocks = 1 exact round, plain += epilogue
    gemm_bt<128, 64, 4, 1, EPI_ADDF32><<<dim3(DM / 64, BT / 128), 256, SM64, stream>>>(
        y, DM, WoT, DM, bo, nullptr, DM, x, DM, nullptr);
    rmsnorm_k<<<BT, 256, 0, stream>>>(x, n2_w, h);
    gemm_bt<128, 128, 2, 2, EPI_GELU><<<dim3(DFF / 128, BT / 128), 256, SM128, stream>>>(
        h, DM, W1T, DM, b1, act, DFF, nullptr, DM, nullptr);
    // MLP2: split-K 2 -> grid (8,16,2)=256 blocks = 1 exact round
    gemm_bt<128, 128, 2, 2, EPI_ATOMIC, 2><<<dim3(DM / 128, BT / 128, 2), 256, SM128, stream>>>(
        act, DFF, W2T, DFF, b2, nullptr, DM, x, DFF, nullptr);
  }

  final_ln_k<<<BT, 256, 0, stream>>>(x, lnf_g, lnf_b, xf);
  gemm8<EPI_F32><<<dim3((NV / 256) * (BT / 256)), 512, 0, stream>>>(
      xf, DM, WlmT, DM, blm, out, NV, DM, BT / 256);
}